// Round 4
// baseline (438.327 us; speedup 1.0000x reference)
//
#include <hip/hip_runtime.h>

// Quantizer: N=65536 rows, D=512, V=512 codes, fp32 in/out.
// score[n,v] = dot(x[n],w[v]) - 0.5*c[v], c[v] = sum_rows w[r][v]^2 (column sums).
// out[n,:] = w[argmax_v score] (== np argmin of -2dot+c).
// k1 v4 (resubmit; R3 bench was an infra failure): fp16 MFMA, rt=4 (64 rows/
// block) -> 32 MFMA per 8 B-loads, 512MB L2 B-traffic. vmcnt-FIFO-aware issue
// order per chunk: convert x_ch, issue B_ch, sched_barrier, issue x_{ch+1}
// prefetch, MFMAs. B-consumption waits vmcnt(8) (x stays in flight); x-convert
// waits vmcnt(0) one full iteration after issue (HBM latency covered). No LDS
// staging, 2 barriers total, acc=128 VGPR, 2 waves/SIMD. EPS 0.18 (~8 sigma of
// fp16 pairwise score error) -> ~1500 flagged rows get exact fp32 re-eval.

#define DIM   512
#define VOCAB 512
#define EPS_GAP 0.18f
#define RBATCH 8

typedef float f32x4 __attribute__((ext_vector_type(4)));
typedef _Float16 f16x8 __attribute__((ext_vector_type(8)));
typedef unsigned long long u64;

__device__ inline u64 packkey(float s, int v){
    unsigned u = __float_as_uint(s);
    u = (u & 0x80000000u) ? ~u : (u | 0x80000000u);   // orderable map
    return (((u64)u) << 32) | (unsigned)(~v);         // low word: bigger = smaller v
}
__device__ inline float keyscore(u64 k){
    unsigned e = (unsigned)(k >> 32);
    return __uint_as_float((e & 0x80000000u) ? (e & 0x7fffffffu) : ~e);
}
__device__ inline int keyv(u64 k){ return (int)(~(unsigned)(k & 0xffffffffu)); }
__device__ inline u64 umax64(u64 a, u64 b){ return a > b ? a : b; }
__device__ inline u64 umin64(u64 a, u64 b){ return a < b ? a : b; }

// ---- prep: c[v] = sum_i w[i][v]^2 (fp64 accum), one wave per column ----
__global__ void colsumsq_kernel(const float* __restrict__ w, float* __restrict__ c){
    const int v = blockIdx.x;              // 512 blocks
    const int lane = threadIdx.x;          // 64
    double s = 0.0;
    for (int i = lane; i < DIM; i += 64){
        const float wv = w[i * VOCAB + v];
        s += (double)wv * (double)wv;
    }
    #pragma unroll
    for (int m = 1; m <= 32; m <<= 1) s += __shfl_xor(s, m, 64);
    if (lane == 0) c[v] = (float)s;
}

// ---- prep: w -> fp16 (RNE), pre-chunked MFMA-fragment layout ----
// element (v,k) -> [chunk=k>>5][g=(k>>3)&3][v][e=k&7]; also zeroes cnt.
// frag(ch, quad, col) = whc[ch*16384 + quad*4096 + col*8 .. +8] (16B contiguous).
__global__ void prep_w(const float* __restrict__ w,
                       _Float16* __restrict__ whc,
                       unsigned* __restrict__ cnt){
    const int i = blockIdx.x * 256 + threadIdx.x;   // 0..262143
    const int v = i >> 9, k = i & 511;
    const int d = (k >> 5) * 16384 + ((k >> 3) & 3) * 4096 + v * 8 + (k & 7);
    whc[d] = (_Float16)w[i];                         // RNE v_cvt_f16_f32
    if (i == 0) *cnt = 0u;
}

// ---- k1: fp16 MFMA scores + top-2 + flag near-ties + fused gather ----
// block 256 thr = 4 waves; block tile 64 rows x 512 cols; grid 1024.
// wave tile: 64 rows x 128 cols (rt=4 x ct=8, 16x16x32 f16 MFMA, 128 acc VGPRs).
__launch_bounds__(256, 2)
__global__ void k1_scores(const float* __restrict__ x,
                          const _Float16* __restrict__ whc,
                          const float* __restrict__ cg,
                          const float* __restrict__ w,
                          float* __restrict__ out,
                          int* __restrict__ list,
                          unsigned* __restrict__ cnt){
    __shared__ u64 mergeK[64][4][2];
    __shared__ int idx_s[64];

    const int t = threadIdx.x;
    const int lane = t & 63, wv = t >> 6, quad = lane >> 4, lm = lane & 15;
    const int cb = wv << 7;                 // wave col base (0,128,256,384)
    const long rbase = (long)blockIdx.x * 64;
    const float* xblk = x + rbase * DIM;

    // acc init = -0.5*c[col] (bias folded; all rows of a lane share its col)
    f32x4 acc[4][8];
    #pragma unroll
    for (int ct = 0; ct < 8; ++ct){
        const float bias = -0.5f * cg[cb + ct * 16 + lm];
        f32x4 z; z[0] = bias; z[1] = bias; z[2] = bias; z[3] = bias;
        #pragma unroll
        for (int rt = 0; rt < 4; ++rt) acc[rt][ct] = z;
    }

    // A fragment pointers: lane (quad,lm) of rt holds
    // x[row = rt*16+lm][k = ch*32 + quad*8 .. +8]
    const float* ap0 = xblk + (long)(lm)      * DIM + quad * 8;
    const float* ap1 = ap0 + 16 * DIM;
    const float* ap2 = ap0 + 32 * DIM;
    const float* ap3 = ap0 + 48 * DIM;

    // prefetch chunk 0 raw A (2x float4 per row-tile)
    float4 ar0a = *(const float4*)(ap0),     ar0b = *(const float4*)(ap0 + 4);
    float4 ar1a = *(const float4*)(ap1),     ar1b = *(const float4*)(ap1 + 4);
    float4 ar2a = *(const float4*)(ap2),     ar2b = *(const float4*)(ap2 + 4);
    float4 ar3a = *(const float4*)(ap3),     ar3b = *(const float4*)(ap3 + 4);

    #pragma unroll 1
    for (int ch = 0; ch < 16; ++ch){
        // (1) convert current chunk's raw A -> fp16 fragments (waits x_ch: vmcnt(0),
        //     but x_ch was issued one full iteration ago)
        f16x8 ah0, ah1, ah2, ah3;
        ah0[0]=(_Float16)ar0a.x; ah0[1]=(_Float16)ar0a.y; ah0[2]=(_Float16)ar0a.z; ah0[3]=(_Float16)ar0a.w;
        ah0[4]=(_Float16)ar0b.x; ah0[5]=(_Float16)ar0b.y; ah0[6]=(_Float16)ar0b.z; ah0[7]=(_Float16)ar0b.w;
        ah1[0]=(_Float16)ar1a.x; ah1[1]=(_Float16)ar1a.y; ah1[2]=(_Float16)ar1a.z; ah1[3]=(_Float16)ar1a.w;
        ah1[4]=(_Float16)ar1b.x; ah1[5]=(_Float16)ar1b.y; ah1[6]=(_Float16)ar1b.z; ah1[7]=(_Float16)ar1b.w;
        ah2[0]=(_Float16)ar2a.x; ah2[1]=(_Float16)ar2a.y; ah2[2]=(_Float16)ar2a.z; ah2[3]=(_Float16)ar2a.w;
        ah2[4]=(_Float16)ar2b.x; ah2[5]=(_Float16)ar2b.y; ah2[6]=(_Float16)ar2b.z; ah2[7]=(_Float16)ar2b.w;
        ah3[0]=(_Float16)ar3a.x; ah3[1]=(_Float16)ar3a.y; ah3[2]=(_Float16)ar3a.z; ah3[3]=(_Float16)ar3a.w;
        ah3[4]=(_Float16)ar3b.x; ah3[5]=(_Float16)ar3b.y; ah3[6]=(_Float16)ar3b.z; ah3[7]=(_Float16)ar3b.w;

        // (2) B loads for this chunk (L2-hot, 16B/lane, 256B/quad contiguous)
        const _Float16* bb = whc + ch * 16384 + quad * 4096 + (cb + lm) * 8;
        f16x8 bh[8];
        #pragma unroll
        for (int ct = 0; ct < 8; ++ct) bh[ct] = *(const f16x8*)(bb + ct * 128);

        // (3) pin issue order: B before x-prefetch, so consuming B waits only
        //     vmcnt(8) (x stays in flight across the MFMA block)
        __builtin_amdgcn_sched_barrier(0);

        // (4) x prefetch for next chunk (last iter reloads ch=15 harmlessly)
        const int chn = (ch < 15) ? ch + 1 : 15;
        ar0a = *(const float4*)(ap0 + chn * 32); ar0b = *(const float4*)(ap0 + chn * 32 + 4);
        ar1a = *(const float4*)(ap1 + chn * 32); ar1b = *(const float4*)(ap1 + chn * 32 + 4);
        ar2a = *(const float4*)(ap2 + chn * 32); ar2b = *(const float4*)(ap2 + chn * 32 + 4);
        ar3a = *(const float4*)(ap3 + chn * 32); ar3b = *(const float4*)(ap3 + chn * 32 + 4);

        // (5) 32 MFMAs, consuming bh[ct] in issue order (progressive vmcnt)
        #pragma unroll
        for (int ct = 0; ct < 8; ++ct){
            acc[0][ct] = __builtin_amdgcn_mfma_f32_16x16x32_f16(ah0, bh[ct], acc[0][ct], 0, 0, 0);
            acc[1][ct] = __builtin_amdgcn_mfma_f32_16x16x32_f16(ah1, bh[ct], acc[1][ct], 0, 0, 0);
            acc[2][ct] = __builtin_amdgcn_mfma_f32_16x16x32_f16(ah2, bh[ct], acc[2][ct], 0, 0, 0);
            acc[3][ct] = __builtin_amdgcn_mfma_f32_16x16x32_f16(ah3, bh[ct], acc[3][ct], 0, 0, 0);
        }
    }

    // epilogue: per-lane top-2 over its 8 cols, lm-merge (16 lanes = 128 cols)
    #pragma unroll
    for (int rt = 0; rt < 4; ++rt){
        #pragma unroll
        for (int reg = 0; reg < 4; ++reg){
            u64 b1 = 0, b2 = 0;
            #pragma unroll
            for (int ct = 0; ct < 8; ++ct){
                const u64 key = packkey(acc[rt][ct][reg], cb + ct * 16 + lm);
                if (key > b1){ b2 = b1; b1 = key; }
                else if (key > b2){ b2 = key; }
            }
            #pragma unroll
            for (int m = 1; m <= 8; m <<= 1){
                const u64 o1 = __shfl_xor(b1, m, 64);
                const u64 o2 = __shfl_xor(b2, m, 64);
                const u64 n1 = umax64(b1, o1);
                b2 = umax64(umin64(b1, o1), umax64(b2, o2));
                b1 = n1;
            }
            if (lm == 0){
                const int row = rt * 16 + quad * 4 + reg;   // 0..63
                mergeK[row][wv][0] = b1;
                mergeK[row][wv][1] = b2;
            }
        }
    }
    __syncthreads();
    if (t < 64){
        u64 p1 = mergeK[t][0][0], p2 = mergeK[t][0][1];
        #pragma unroll
        for (int i = 1; i < 4; ++i){
            const u64 q1 = mergeK[t][i][0], q2 = mergeK[t][i][1];
            const u64 n1 = umax64(p1, q1);
            p2 = umax64(umin64(p1, q1), umax64(p2, q2));
            p1 = n1;
        }
        idx_s[t] = keyv(p1);
        if (keyscore(p1) - keyscore(p2) < EPS_GAP){
            const unsigned p = atomicAdd(cnt, 1u);
            list[p] = (int)(rbase + t);
        }
    }
    __syncthreads();

    // fused gather: 64 rows x 512 floats, 2 rows / iteration
    for (int rr = 0; rr < 64; rr += 2){
        const int row  = rr + (t >> 7);
        const int col  = (t & 127) << 2;
        const int vidx = idx_s[row];
        const float4 val = *(const float4*)(w + (long)vidx * DIM + col);
        *(float4*)(out + (rbase + row) * DIM + col) = val;
    }
}

// ---- exact fp32 re-check + rewrite for flagged (near-tie) rows, BATCHED ----
// 8 rows per block: x rows staged in LDS (16KB), each thread scores 2 codes
// for all 8 rows (w read once per batch from L2), then per-row argmax + rewrite.
__global__ void refine_rows(const float* __restrict__ x, const float* __restrict__ w,
                            const float* __restrict__ cg, const int* __restrict__ list,
                            const unsigned* __restrict__ cnt, float* __restrict__ out){
    __shared__ __align__(16) float xs[RBATCH][DIM];
    __shared__ u64 wk[RBATCH][4];
    __shared__ int bestv_s[RBATCH];
    const int t = threadIdx.x;
    const int lane = t & 63, wvq = t >> 6;
    const int n = (int)*cnt;
    for (int base = blockIdx.x * RBATCH; base < n; base += gridDim.x * RBATCH){
        const int m = (n - base < RBATCH) ? (n - base) : RBATCH;
        __syncthreads();   // protect xs/bestv_s reuse across iterations
        for (int s = t; s < m * 128; s += 256){
            const int r = s >> 7, c = (s & 127) << 2;
            *(float4*)&xs[r][c] = *(const float4*)(x + (long)list[base + r] * DIM + c);
        }
        __syncthreads();
        u64 best[RBATCH];
        #pragma unroll
        for (int r = 0; r < RBATCH; ++r) best[r] = 0;
        #pragma unroll
        for (int vv = 0; vv < 2; ++vv){
            const int v = t + vv * 256;
            const float* wr = w + (long)v * DIM;
            float s[RBATCH];
            #pragma unroll
            for (int r = 0; r < RBATCH; ++r) s[r] = -0.5f * cg[v];
            for (int k = 0; k < DIM; k += 4){
                const float4 w4 = *(const float4*)(wr + k);
                #pragma unroll
                for (int r = 0; r < RBATCH; ++r){
                    const float4 x4 = *(const float4*)&xs[r][k];
                    s[r] = fmaf(w4.x, x4.x, s[r]);
                    s[r] = fmaf(w4.y, x4.y, s[r]);
                    s[r] = fmaf(w4.z, x4.z, s[r]);
                    s[r] = fmaf(w4.w, x4.w, s[r]);
                }
            }
            #pragma unroll
            for (int r = 0; r < RBATCH; ++r)
                best[r] = umax64(best[r], packkey(s[r], v));
        }
        #pragma unroll
        for (int r = 0; r < RBATCH; ++r){
            u64 b = best[r];
            #pragma unroll
            for (int mm = 1; mm <= 32; mm <<= 1) b = umax64(b, __shfl_xor(b, mm, 64));
            if (lane == 0) wk[r][wvq] = b;
        }
        __syncthreads();
        if (t < RBATCH){
            const u64 b = umax64(umax64(wk[t][0], wk[t][1]), umax64(wk[t][2], wk[t][3]));
            bestv_s[t] = keyv(b);
        }
        __syncthreads();
        for (int s = t; s < m * 128; s += 256){
            const int r = s >> 7, c = (s & 127) << 2;
            *(float4*)(out + (long)list[base + r] * DIM + c) =
                *(const float4*)(w + (long)bestv_s[r] * DIM + c);
        }
    }
}

// ---- fallback: round-1 fp32 kernel (self-contained, no ws) ----
__launch_bounds__(256)
__global__ void fallback_full(const float* __restrict__ x, const float* __restrict__ w,
                              float* __restrict__ out){
    __shared__ __align__(16) float As[16][68];
    __shared__ __align__(16) float Bs[16][VOCAB];
    __shared__ int   idx_sf[64];
    __shared__ float c_s[VOCAB];

    const int t  = threadIdx.x;
    const int tx = t & 31;
    const int ty = t >> 5;
    const long rbase = (long)blockIdx.x * 64;
    const float* xblk = x + rbase * DIM;

    for (int vv = t; vv < VOCAB; vv += 256){
        double s = 0.0;
        for (int i = 0; i < DIM; ++i){
            const float wvv = w[i * VOCAB + vv];
            s += (double)wvv * (double)wvv;
        }
        c_s[vv] = (float)s;
    }

    float acc[8][16];
    #pragma unroll
    for (int r = 0; r < 8; ++r)
        #pragma unroll
        for (int j = 0; j < 16; ++j) acc[r][j] = 0.0f;

    for (int k0 = 0; k0 < DIM; k0 += 16){
        __syncthreads();
        {
            const int r  = t >> 2;
            const int kq = (t & 3) << 2;
            const float4 a4 = *(const float4*)(xblk + (long)r * DIM + k0 + kq);
            As[kq + 0][r] = a4.x; As[kq + 1][r] = a4.y;
            As[kq + 2][r] = a4.z; As[kq + 3][r] = a4.w;
        }
        #pragma unroll
        for (int vb = 0; vb < 8; ++vb){
            const int v  = (t >> 2) + (vb << 6);
            const int kq = (t & 3) << 2;
            const float4 b4 = *(const float4*)(w + (long)v * DIM + k0 + kq);
            Bs[kq + 0][v] = b4.x; Bs[kq + 1][v] = b4.y;
            Bs[kq + 2][v] = b4.z; Bs[kq + 3][v] = b4.w;
        }
        __syncthreads();

        #pragma unroll
        for (int k = 0; k < 16; ++k){
            float a[8];
            const float4 a03 = *(const float4*)&As[k][ty * 8];
            const float4 a47 = *(const float4*)&As[k][ty * 8 + 4];
            a[0] = a03.x; a[1] = a03.y; a[2] = a03.z; a[3] = a03.w;
            a[4] = a47.x; a[5] = a47.y; a[6] = a47.z; a[7] = a47.w;
            float b[16];
            #pragma unroll
            for (int j = 0; j < 16; ++j) b[j] = Bs[k][tx + (j << 5)];
            #pragma unroll
            for (int r = 0; r < 8; ++r)
                #pragma unroll
                for (int j = 0; j < 16; ++j)
                    acc[r][j] = fmaf(a[r], b[j], acc[r][j]);
        }
    }

    #pragma unroll
    for (int r = 0; r < 8; ++r){
        float best = acc[r][0] - 0.5f * c_s[tx];
        int   bv   = tx;
        #pragma unroll
        for (int j = 1; j < 16; ++j){
            const float s = acc[r][j] - 0.5f * c_s[tx + (j << 5)];
            if (s > best){ best = s; bv = tx + (j << 5); }
        }
        unsigned u = __float_as_uint(best);
        u = (u & 0x80000000u) ? ~u : (u | 0x80000000u);
        u64 key = ((u64)u << 32) | (unsigned)(~(unsigned)bv);
        #pragma unroll
        for (int m = 1; m <= 16; m <<= 1){
            const u64 o = __shfl_xor(key, m, 64);
            if (o > key) key = o;
        }
        if (tx == 0) idx_sf[ty * 8 + r] = (int)(~(unsigned)(key & 0xFFFFFFFFull));
    }
    __syncthreads();

    for (int rr = 0; rr < 64; rr += 2){
        const int row  = rr + (t >> 7);
        const int col  = (t & 127) << 2;
        const int vidx = idx_sf[row];
        const float4 val = *(const float4*)(w + (long)vidx * DIM + col);
        *(float4*)(out + (rbase + row) * DIM + col) = val;
    }
}

extern "C" void kernel_launch(void* const* d_in, const int* in_sizes, int n_in,
                              void* d_out, int out_size, void* d_ws, size_t ws_size,
                              hipStream_t stream){
    const float* x = (const float*)d_in[0];
    const float* w = (const float*)d_in[1];
    float* out = (float*)d_out;
    const int rows = in_sizes[0] / DIM;        // 65536

    // ws layout (bytes)
    const size_t whc_off  = 0;
    const size_t c_off    = whc_off + (size_t)DIM * VOCAB * 2;   // 512KB fp16 w
    const size_t list_off = c_off   + (size_t)VOCAB * 4;
    const size_t cnt_off  = list_off + (size_t)rows * 4;
    const size_t need     = cnt_off + 16;

    if (ws_size >= need){
        _Float16* whc  = (_Float16*)((char*)d_ws + whc_off);
        float*    c    = (float*)((char*)d_ws + c_off);
        int*      list = (int*)((char*)d_ws + list_off);
        unsigned* cnt  = (unsigned*)((char*)d_ws + cnt_off);

        prep_w<<<(DIM * VOCAB) / 256, 256, 0, stream>>>(w, whc, cnt);
        colsumsq_kernel<<<VOCAB, 64, 0, stream>>>(w, c);
        k1_scores<<<rows / 64, 256, 0, stream>>>(x, whc, c, w, out, list, cnt);
        refine_rows<<<512, 256, 0, stream>>>(x, w, c, list, cnt, out);
    } else {
        fallback_full<<<rows / 64, 256, 0, stream>>>(x, w, out);
    }
}

// Round 5
// 334.199 us; speedup vs baseline: 1.3116x; 1.3116x over previous
//
#include <hip/hip_runtime.h>

// Quantizer: N=65536 rows, D=512, V=512 codes, fp32 in/out.
// score[n,v] = dot(x[n],w[v]) - 0.5*c[v], c[v] = sum_rows w[r][v]^2 (column sums).
// out[n,:] = w[argmax_v score] (== np argmin of -2dot+c).
// k1 v5 = R1's proven staging structure (coalesced global x reads -> in-reg
// cvt -> LDS fragment layout, 2 half-K batches, 4 barriers total, barrier-free
// 8-chunk inner loop) with SINGLE fp16 MFMA (1/3 of R1's split-bf16 work).
// R2/R4's per-lane direct-from-global A loads were the regression: 2KB lane
// stride = 64 cache lines per load instruction (uncoalesced scatter). R1's
// staging reads 128B-contiguous per row. B (whc fp16, 512KB, L2-resident) is
// read as per-lane 16B fragments (prep layout == fragment layout).
// fp16 score err rms ~0.009; EPS 0.18 -> ~1500 flagged rows get exact fp32
// re-eval in batched refine (8 rows/block, w read once per batch from L2).

#define DIM   512
#define VOCAB 512
#define EPS_GAP 0.18f
#define RBATCH 8

typedef float f32x4 __attribute__((ext_vector_type(4)));
typedef _Float16 f16x8 __attribute__((ext_vector_type(8)));
typedef unsigned long long u64;

__device__ inline u64 packkey(float s, int v){
    unsigned u = __float_as_uint(s);
    u = (u & 0x80000000u) ? ~u : (u | 0x80000000u);   // orderable map
    return (((u64)u) << 32) | (unsigned)(~v);         // low word: bigger = smaller v
}
__device__ inline float keyscore(u64 k){
    unsigned e = (unsigned)(k >> 32);
    return __uint_as_float((e & 0x80000000u) ? (e & 0x7fffffffu) : ~e);
}
__device__ inline int keyv(u64 k){ return (int)(~(unsigned)(k & 0xffffffffu)); }
__device__ inline u64 umax64(u64 a, u64 b){ return a > b ? a : b; }
__device__ inline u64 umin64(u64 a, u64 b){ return a < b ? a : b; }

// ---- prep: c[v] = sum_i w[i][v]^2 (fp64 accum), one wave per column ----
__global__ void colsumsq_kernel(const float* __restrict__ w, float* __restrict__ c){
    const int v = blockIdx.x;              // 512 blocks
    const int lane = threadIdx.x;          // 64
    double s = 0.0;
    for (int i = lane; i < DIM; i += 64){
        const float wv = w[i * VOCAB + v];
        s += (double)wv * (double)wv;
    }
    #pragma unroll
    for (int m = 1; m <= 32; m <<= 1) s += __shfl_xor(s, m, 64);
    if (lane == 0) c[v] = (float)s;
}

// ---- prep: w -> fp16 (RNE), pre-chunked MFMA-fragment layout ----
// element (v,k) -> [chunk=k>>5][g=(k>>3)&3][v][e=k&7]; also zeroes cnt.
// frag(ch, quad, col) = whc[ch*16384 + quad*4096 + col*8 .. +8] (16B contiguous).
__global__ void prep_w(const float* __restrict__ w,
                       _Float16* __restrict__ whc,
                       unsigned* __restrict__ cnt){
    const int i = blockIdx.x * 256 + threadIdx.x;   // 0..262143
    const int v = i >> 9, k = i & 511;
    const int d = (k >> 5) * 16384 + ((k >> 3) & 3) * 4096 + v * 8 + (k & 7);
    whc[d] = (_Float16)w[i];                         // RNE v_cvt_f16_f32
    if (i == 0) *cnt = 0u;
}

// ---- k1: fp16 MFMA scores + top-2 + flag near-ties + fused gather ----
// block 256 thr = 4 waves; block tile 64 rows x 512 cols; grid 1024.
// wave tile: 64 rows x 128 cols (rt=4 x ct=8, 16x16x32 f16 MFMA, 128 acc regs).
// A staged in LDS per half-K (64 rows x 256 k fp16, 32KB); B fragments read
// directly from global (L2-hot). LDS ~37KB. 4 barriers total.
__launch_bounds__(256, 2)
__global__ void k1_scores(const float* __restrict__ x,
                          const _Float16* __restrict__ whc,
                          const float* __restrict__ cg,
                          const float* __restrict__ w,
                          float* __restrict__ out,
                          int* __restrict__ list,
                          unsigned* __restrict__ cnt){
    __shared__ __align__(16) _Float16 Ah[16384];  // [ch2=8][quad=4][row=64][8]
    __shared__ u64 mergeK[64][4][2];
    __shared__ int idx_s[64];

    const int t = threadIdx.x;
    const int lane = t & 63, wv = t >> 6, quad = lane >> 4, lm = lane & 15;
    const int cb = wv << 7;                 // wave col base (0,128,256,384)
    const long rbase = (long)blockIdx.x * 64;
    const float* xblk = x + rbase * DIM;

    // acc init = -0.5*c[col] (bias folded; all rows of a lane share its col)
    f32x4 acc[4][8];
    #pragma unroll
    for (int ct = 0; ct < 8; ++ct){
        const float bias = -0.5f * cg[cb + ct * 16 + lm];
        f32x4 z; z[0] = bias; z[1] = bias; z[2] = bias; z[3] = bias;
        #pragma unroll
        for (int rt = 0; rt < 4; ++rt) acc[rt][ct] = z;
    }

    for (int half = 0; half < 2; ++half){
        __syncthreads();   // protect Ah reuse (half 1)
        // stage A half: 64 rows x 256 k fp32 -> fp16 fragment layout.
        // j bits: [2:0]=k4-low, [8:3]=row, [11:9]=ch2. Per wave: 8 rows x 128B
        // coalesced global reads (8 lines/instr); ds_write ~4-way conflict
        // (proven R1 pattern).
        #pragma unroll 8
        for (int jj = 0; jj < 16; ++jj){
            const int j   = jj * 256 + t;                 // 0..4095 float4 slots
            const int row = (j >> 3) & 63;
            const int k4  = (j & 7) | ((j >> 9) << 3);    // 0..63
            const int kk  = k4 << 2;                      // 0..255, 4-aligned
            const float4 a4 = *(const float4*)(xblk + (long)row * DIM + half * 256 + kk);
            union { _Float16 h[4]; ushort4 u; } cv;
            cv.h[0] = (_Float16)a4.x;
            cv.h[1] = (_Float16)a4.y;
            cv.h[2] = (_Float16)a4.z;
            cv.h[3] = (_Float16)a4.w;
            const int d = (((kk >> 5) * 4 + ((kk >> 3) & 3)) * 64 + row) * 8 + (kk & 7);
            *(ushort4*)&Ah[d] = cv.u;
        }
        __syncthreads();

        // barrier-free inner loop over the 8 chunks of this half
        for (int ch2 = 0; ch2 < 8; ++ch2){
            const int ch = half * 8 + ch2;
            // A frags from LDS: row = rt*16 + lm, k = quad*8 + j (verified R1)
            f16x8 ah[4];
            #pragma unroll
            for (int rt = 0; rt < 4; ++rt){
                const int d = ((ch2 * 4 + quad) * 64 + rt * 16 + lm) * 8;
                ah[rt] = *(const f16x8*)&Ah[d];
            }
            // B frags direct from global (L2-hot, 16B/lane, 256B/quad contiguous)
            const _Float16* bb = whc + ch * 16384 + quad * 4096;
            #pragma unroll
            for (int ct = 0; ct < 8; ++ct){
                const f16x8 bh = *(const f16x8*)(bb + (cb + ct * 16 + lm) * 8);
                #pragma unroll
                for (int rt = 0; rt < 4; ++rt)
                    acc[rt][ct] = __builtin_amdgcn_mfma_f32_16x16x32_f16(ah[rt], bh, acc[rt][ct], 0, 0, 0);
            }
        }
    }

    // epilogue: per-lane top-2 over its 8 cols, lm-merge (16 lanes = 128 cols)
    #pragma unroll
    for (int rt = 0; rt < 4; ++rt){
        #pragma unroll
        for (int reg = 0; reg < 4; ++reg){
            u64 b1 = 0, b2 = 0;
            #pragma unroll
            for (int ct = 0; ct < 8; ++ct){
                const u64 key = packkey(acc[rt][ct][reg], cb + ct * 16 + lm);
                if (key > b1){ b2 = b1; b1 = key; }
                else if (key > b2){ b2 = key; }
            }
            #pragma unroll
            for (int m = 1; m <= 8; m <<= 1){
                const u64 o1 = __shfl_xor(b1, m, 64);
                const u64 o2 = __shfl_xor(b2, m, 64);
                const u64 n1 = umax64(b1, o1);
                b2 = umax64(umin64(b1, o1), umax64(b2, o2));
                b1 = n1;
            }
            if (lm == 0){
                const int row = rt * 16 + quad * 4 + reg;   // 0..63
                mergeK[row][wv][0] = b1;
                mergeK[row][wv][1] = b2;
            }
        }
    }
    __syncthreads();
    if (t < 64){
        u64 p1 = mergeK[t][0][0], p2 = mergeK[t][0][1];
        #pragma unroll
        for (int i = 1; i < 4; ++i){
            const u64 q1 = mergeK[t][i][0], q2 = mergeK[t][i][1];
            const u64 n1 = umax64(p1, q1);
            p2 = umax64(umin64(p1, q1), umax64(p2, q2));
            p1 = n1;
        }
        idx_s[t] = keyv(p1);
        if (keyscore(p1) - keyscore(p2) < EPS_GAP){
            const unsigned p = atomicAdd(cnt, 1u);
            list[p] = (int)(rbase + t);
        }
    }
    __syncthreads();

    // fused gather: 64 rows x 512 floats, 2 rows / iteration
    for (int rr = 0; rr < 64; rr += 2){
        const int row  = rr + (t >> 7);
        const int col  = (t & 127) << 2;
        const int vidx = idx_s[row];
        const float4 val = *(const float4*)(w + (long)vidx * DIM + col);
        *(float4*)(out + (rbase + row) * DIM + col) = val;
    }
}

// ---- exact fp32 re-check + rewrite for flagged (near-tie) rows, BATCHED ----
// 8 rows per block: x rows staged in LDS (16KB), each thread scores 2 codes
// for all 8 rows (w read once per batch from L2), then per-row argmax + rewrite.
__global__ void refine_rows(const float* __restrict__ x, const float* __restrict__ w,
                            const float* __restrict__ cg, const int* __restrict__ list,
                            const unsigned* __restrict__ cnt, float* __restrict__ out){
    __shared__ __align__(16) float xs[RBATCH][DIM];
    __shared__ u64 wk[RBATCH][4];
    __shared__ int bestv_s[RBATCH];
    const int t = threadIdx.x;
    const int lane = t & 63, wvq = t >> 6;
    const int n = (int)*cnt;
    for (int base = blockIdx.x * RBATCH; base < n; base += gridDim.x * RBATCH){
        const int m = (n - base < RBATCH) ? (n - base) : RBATCH;
        __syncthreads();   // protect xs/bestv_s reuse across iterations
        for (int s = t; s < m * 128; s += 256){
            const int r = s >> 7, c = (s & 127) << 2;
            *(float4*)&xs[r][c] = *(const float4*)(x + (long)list[base + r] * DIM + c);
        }
        __syncthreads();
        u64 best[RBATCH];
        #pragma unroll
        for (int r = 0; r < RBATCH; ++r) best[r] = 0;
        #pragma unroll
        for (int vv = 0; vv < 2; ++vv){
            const int v = t + vv * 256;
            const float* wr = w + (long)v * DIM;
            float s[RBATCH];
            #pragma unroll
            for (int r = 0; r < RBATCH; ++r) s[r] = -0.5f * cg[v];
            for (int k = 0; k < DIM; k += 4){
                const float4 w4 = *(const float4*)(wr + k);
                #pragma unroll
                for (int r = 0; r < RBATCH; ++r){
                    const float4 x4 = *(const float4*)&xs[r][k];
                    s[r] = fmaf(w4.x, x4.x, s[r]);
                    s[r] = fmaf(w4.y, x4.y, s[r]);
                    s[r] = fmaf(w4.z, x4.z, s[r]);
                    s[r] = fmaf(w4.w, x4.w, s[r]);
                }
            }
            #pragma unroll
            for (int r = 0; r < RBATCH; ++r)
                best[r] = umax64(best[r], packkey(s[r], v));
        }
        #pragma unroll
        for (int r = 0; r < RBATCH; ++r){
            u64 b = best[r];
            #pragma unroll
            for (int mm = 1; mm <= 32; mm <<= 1) b = umax64(b, __shfl_xor(b, mm, 64));
            if (lane == 0) wk[r][wvq] = b;
        }
        __syncthreads();
        if (t < RBATCH){
            const u64 b = umax64(umax64(wk[t][0], wk[t][1]), umax64(wk[t][2], wk[t][3]));
            bestv_s[t] = keyv(b);
        }
        __syncthreads();
        for (int s = t; s < m * 128; s += 256){
            const int r = s >> 7, c = (s & 127) << 2;
            *(float4*)(out + (long)list[base + r] * DIM + c) =
                *(const float4*)(w + (long)bestv_s[r] * DIM + c);
        }
    }
}

// ---- fallback: round-1 fp32 kernel (self-contained, no ws) ----
__launch_bounds__(256)
__global__ void fallback_full(const float* __restrict__ x, const float* __restrict__ w,
                              float* __restrict__ out){
    __shared__ __align__(16) float As[16][68];
    __shared__ __align__(16) float Bs[16][VOCAB];
    __shared__ int   idx_sf[64];
    __shared__ float c_s[VOCAB];

    const int t  = threadIdx.x;
    const int tx = t & 31;
    const int ty = t >> 5;
    const long rbase = (long)blockIdx.x * 64;
    const float* xblk = x + rbase * DIM;

    for (int vv = t; vv < VOCAB; vv += 256){
        double s = 0.0;
        for (int i = 0; i < DIM; ++i){
            const float wvv = w[i * VOCAB + vv];
            s += (double)wvv * (double)wvv;
        }
        c_s[vv] = (float)s;
    }

    float acc[8][16];
    #pragma unroll
    for (int r = 0; r < 8; ++r)
        #pragma unroll
        for (int j = 0; j < 16; ++j) acc[r][j] = 0.0f;

    for (int k0 = 0; k0 < DIM; k0 += 16){
        __syncthreads();
        {
            const int r  = t >> 2;
            const int kq = (t & 3) << 2;
            const float4 a4 = *(const float4*)(xblk + (long)r * DIM + k0 + kq);
            As[kq + 0][r] = a4.x; As[kq + 1][r] = a4.y;
            As[kq + 2][r] = a4.z; As[kq + 3][r] = a4.w;
        }
        #pragma unroll
        for (int vb = 0; vb < 8; ++vb){
            const int v  = (t >> 2) + (vb << 6);
            const int kq = (t & 3) << 2;
            const float4 b4 = *(const float4*)(w + (long)v * DIM + k0 + kq);
            Bs[kq + 0][v] = b4.x; Bs[kq + 1][v] = b4.y;
            Bs[kq + 2][v] = b4.z; Bs[kq + 3][v] = b4.w;
        }
        __syncthreads();

        #pragma unroll
        for (int k = 0; k < 16; ++k){
            float a[8];
            const float4 a03 = *(const float4*)&As[k][ty * 8];
            const float4 a47 = *(const float4*)&As[k][ty * 8 + 4];
            a[0] = a03.x; a[1] = a03.y; a[2] = a03.z; a[3] = a03.w;
            a[4] = a47.x; a[5] = a47.y; a[6] = a47.z; a[7] = a47.w;
            float b[16];
            #pragma unroll
            for (int j = 0; j < 16; ++j) b[j] = Bs[k][tx + (j << 5)];
            #pragma unroll
            for (int r = 0; r < 8; ++r)
                #pragma unroll
                for (int j = 0; j < 16; ++j)
                    acc[r][j] = fmaf(a[r], b[j], acc[r][j]);
        }
    }

    #pragma unroll
    for (int r = 0; r < 8; ++r){
        float best = acc[r][0] - 0.5f * c_s[tx];
        int   bv   = tx;
        #pragma unroll
        for (int j = 1; j < 16; ++j){
            const float s = acc[r][j] - 0.5f * c_s[tx + (j << 5)];
            if (s > best){ best = s; bv = tx + (j << 5); }
        }
        unsigned u = __float_as_uint(best);
        u = (u & 0x80000000u) ? ~u : (u | 0x80000000u);
        u64 key = ((u64)u << 32) | (unsigned)(~(unsigned)bv);
        #pragma unroll
        for (int m = 1; m <= 16; m <<= 1){
            const u64 o = __shfl_xor(key, m, 64);
            if (o > key) key = o;
        }
        if (tx == 0) idx_sf[ty * 8 + r] = (int)(~(unsigned)(key & 0xFFFFFFFFull));
    }
    __syncthreads();

    for (int rr = 0; rr < 64; rr += 2){
        const int row  = rr + (t >> 7);
        const int col  = (t & 127) << 2;
        const int vidx = idx_sf[row];
        const float4 val = *(const float4*)(w + (long)vidx * DIM + col);
        *(float4*)(out + (rbase + row) * DIM + col) = val;
    }
}

extern "C" void kernel_launch(void* const* d_in, const int* in_sizes, int n_in,
                              void* d_out, int out_size, void* d_ws, size_t ws_size,
                              hipStream_t stream){
    const float* x = (const float*)d_in[0];
    const float* w = (const float*)d_in[1];
    float* out = (float*)d_out;
    const int rows = in_sizes[0] / DIM;        // 65536

    // ws layout (bytes)
    const size_t whc_off  = 0;
    const size_t c_off    = whc_off + (size_t)DIM * VOCAB * 2;   // 512KB fp16 w
    const size_t list_off = c_off   + (size_t)VOCAB * 4;
    const size_t cnt_off  = list_off + (size_t)rows * 4;
    const size_t need     = cnt_off + 16;

    if (ws_size >= need){
        _Float16* whc  = (_Float16*)((char*)d_ws + whc_off);
        float*    c    = (float*)((char*)d_ws + c_off);
        int*      list = (int*)((char*)d_ws + list_off);
        unsigned* cnt  = (unsigned*)((char*)d_ws + cnt_off);

        prep_w<<<(DIM * VOCAB) / 256, 256, 0, stream>>>(w, whc, cnt);
        colsumsq_kernel<<<VOCAB, 64, 0, stream>>>(w, c);
        k1_scores<<<rows / 64, 256, 0, stream>>>(x, whc, c, w, out, list, cnt);
        refine_rows<<<512, 256, 0, stream>>>(x, w, c, list, cnt, out);
    } else {
        fallback_full<<<rows / 64, 256, 0, stream>>>(x, w, out);
    }
}

// Round 6
// 330.973 us; speedup vs baseline: 1.3244x; 1.0097x over previous
//
#include <hip/hip_runtime.h>

// Quantizer: N=65536 rows, D=512, V=512 codes, fp32 in/out.
// score[n,v] = dot(x[n],w[v]) - 0.5*c[v], c[v] = sum_rows w[r][v]^2 (column sums).
// out[n,:] = w[argmax_v score] (== np argmin of -2dot+c).
// k1 v6: occupancy fix. R5 was 2 waves/SIMD (124 VGPR + 128 acc-AGPR = 252
// unified regs) -> 73% idle. v6: rt=2 (32 rows/block, grid 2048), acc=64 AGPR,
// launch_bounds(256,4) caps total at 128 -> 4 waves/SIMD; full-K staged once
// (32 rows x 512 k fp16 = 32KB LDS, ~34.4KB total -> 4 blocks/CU). 3 barriers
// total; 16-chunk inner loop barrier-free. B (whc fp16, 512KB, L2-resident)
// read as per-lane 16B fragments (prep layout == fragment layout).
// fp16 score err rms ~0.009; EPS 0.18 -> ~1500 flagged rows get exact fp32
// re-eval in batched refine (8 rows/block, w read once per batch from L2).

#define DIM   512
#define VOCAB 512
#define EPS_GAP 0.18f
#define RBATCH 8

typedef float f32x4 __attribute__((ext_vector_type(4)));
typedef _Float16 f16x8 __attribute__((ext_vector_type(8)));
typedef unsigned long long u64;

__device__ inline u64 packkey(float s, int v){
    unsigned u = __float_as_uint(s);
    u = (u & 0x80000000u) ? ~u : (u | 0x80000000u);   // orderable map
    return (((u64)u) << 32) | (unsigned)(~v);         // low word: bigger = smaller v
}
__device__ inline float keyscore(u64 k){
    unsigned e = (unsigned)(k >> 32);
    return __uint_as_float((e & 0x80000000u) ? (e & 0x7fffffffu) : ~e);
}
__device__ inline int keyv(u64 k){ return (int)(~(unsigned)(k & 0xffffffffu)); }
__device__ inline u64 umax64(u64 a, u64 b){ return a > b ? a : b; }
__device__ inline u64 umin64(u64 a, u64 b){ return a < b ? a : b; }

// ---- prep: c[v] = sum_i w[i][v]^2 (fp64 accum), one wave per column ----
__global__ void colsumsq_kernel(const float* __restrict__ w, float* __restrict__ c){
    const int v = blockIdx.x;              // 512 blocks
    const int lane = threadIdx.x;          // 64
    double s = 0.0;
    for (int i = lane; i < DIM; i += 64){
        const float wv = w[i * VOCAB + v];
        s += (double)wv * (double)wv;
    }
    #pragma unroll
    for (int m = 1; m <= 32; m <<= 1) s += __shfl_xor(s, m, 64);
    if (lane == 0) c[v] = (float)s;
}

// ---- prep: w -> fp16 (RNE), pre-chunked MFMA-fragment layout ----
// element (v,k) -> [chunk=k>>5][g=(k>>3)&3][v][e=k&7]; also zeroes cnt.
// frag(ch, quad, col) = whc[ch*16384 + quad*4096 + col*8 .. +8] (16B contiguous).
__global__ void prep_w(const float* __restrict__ w,
                       _Float16* __restrict__ whc,
                       unsigned* __restrict__ cnt){
    const int i = blockIdx.x * 256 + threadIdx.x;   // 0..262143
    const int v = i >> 9, k = i & 511;
    const int d = (k >> 5) * 16384 + ((k >> 3) & 3) * 4096 + v * 8 + (k & 7);
    whc[d] = (_Float16)w[i];                         // RNE v_cvt_f16_f32
    if (i == 0) *cnt = 0u;
}

// ---- k1: fp16 MFMA scores + top-2 + flag near-ties + fused gather ----
// block 256 thr = 4 waves; block tile 32 rows x 512 cols; grid 2048.
// wave tile: 32 rows x 128 cols (rt=2 x ct=8, 16x16x32 f16 MFMA, 64 acc regs).
// A staged in LDS once (32 rows x 512 k fp16, 32KB); B fragments read directly
// from global (L2-hot). LDS ~34.4KB -> 4 blocks/CU. 3 barriers total.
__launch_bounds__(256, 4)
__global__ void k1_scores(const float* __restrict__ x,
                          const _Float16* __restrict__ whc,
                          const float* __restrict__ cg,
                          const float* __restrict__ w,
                          float* __restrict__ out,
                          int* __restrict__ list,
                          unsigned* __restrict__ cnt){
    __shared__ __align__(16) _Float16 Ah[16384];  // [ch=16][quad=4][row=32][8]
    __shared__ u64 mergeK[32][4][2];
    __shared__ int idx_s[32];

    const int t = threadIdx.x;
    const int lane = t & 63, wv = t >> 6, quad = lane >> 4, lm = lane & 15;
    const int cb = wv << 7;                 // wave col base (0,128,256,384)
    const long rbase = (long)blockIdx.x * 32;
    const float* xblk = x + rbase * DIM;

    // acc init = -0.5*c[col] (bias folded; all rows of a lane share its col)
    f32x4 acc[2][8];
    #pragma unroll
    for (int ct = 0; ct < 8; ++ct){
        const float bias = -0.5f * cg[cb + ct * 16 + lm];
        f32x4 z; z[0] = bias; z[1] = bias; z[2] = bias; z[3] = bias;
        acc[0][ct] = z; acc[1][ct] = z;
    }

    // stage A: 32 rows x 512 k fp32 -> fp16 fragment layout (one shot).
    // Thread t owns row t>>3, walks k by 32 floats per jj: coalesced
    // 128B-contiguous per 8-lane row-group; ds_write 4-way conflict
    // (same proven pattern as R1/R5).
    #pragma unroll 4
    for (int jj = 0; jj < 16; ++jj){
        const int j   = jj * 256 + t;                 // 0..4095 float4 slots
        const int row = (j >> 3) & 31;
        const int k4  = (j & 7) | ((j >> 8) << 3);    // 0..127
        const int kk  = k4 << 2;                      // 0..508, 4-aligned
        const float4 a4 = *(const float4*)(xblk + (long)row * DIM + kk);
        union { _Float16 h[4]; ushort4 u; } cv;
        cv.h[0] = (_Float16)a4.x;
        cv.h[1] = (_Float16)a4.y;
        cv.h[2] = (_Float16)a4.z;
        cv.h[3] = (_Float16)a4.w;
        const int d = (((kk >> 5) * 4 + ((kk >> 3) & 3)) * 32 + row) * 8 + (kk & 7);
        *(ushort4*)&Ah[d] = cv.u;
    }
    __syncthreads();

    // barrier-free inner loop over all 16 chunks
    for (int ch = 0; ch < 16; ++ch){
        // A frags from LDS: row = rt*16 + lm, k = quad*8 + j (verified R1/R5)
        f16x8 ah0 = *(const f16x8*)&Ah[((ch * 4 + quad) * 32 + lm) * 8];
        f16x8 ah1 = *(const f16x8*)&Ah[((ch * 4 + quad) * 32 + 16 + lm) * 8];
        // B frags direct from global (L2-hot, 16B/lane, 256B/quad contiguous)
        const _Float16* bb = whc + ch * 16384 + quad * 4096;
        #pragma unroll
        for (int ct = 0; ct < 8; ++ct){
            const f16x8 bh = *(const f16x8*)(bb + (cb + ct * 16 + lm) * 8);
            acc[0][ct] = __builtin_amdgcn_mfma_f32_16x16x32_f16(ah0, bh, acc[0][ct], 0, 0, 0);
            acc[1][ct] = __builtin_amdgcn_mfma_f32_16x16x32_f16(ah1, bh, acc[1][ct], 0, 0, 0);
        }
    }

    // epilogue: per-lane top-2 over its 8 cols, lm-merge (16 lanes = 128 cols)
    #pragma unroll
    for (int rt = 0; rt < 2; ++rt){
        #pragma unroll
        for (int reg = 0; reg < 4; ++reg){
            u64 b1 = 0, b2 = 0;
            #pragma unroll
            for (int ct = 0; ct < 8; ++ct){
                const u64 key = packkey(acc[rt][ct][reg], cb + ct * 16 + lm);
                if (key > b1){ b2 = b1; b1 = key; }
                else if (key > b2){ b2 = key; }
            }
            #pragma unroll
            for (int m = 1; m <= 8; m <<= 1){
                const u64 o1 = __shfl_xor(b1, m, 64);
                const u64 o2 = __shfl_xor(b2, m, 64);
                const u64 n1 = umax64(b1, o1);
                b2 = umax64(umin64(b1, o1), umax64(b2, o2));
                b1 = n1;
            }
            if (lm == 0){
                const int row = rt * 16 + quad * 4 + reg;   // 0..31
                mergeK[row][wv][0] = b1;
                mergeK[row][wv][1] = b2;
            }
        }
    }
    __syncthreads();
    if (t < 32){
        u64 p1 = mergeK[t][0][0], p2 = mergeK[t][0][1];
        #pragma unroll
        for (int i = 1; i < 4; ++i){
            const u64 q1 = mergeK[t][i][0], q2 = mergeK[t][i][1];
            const u64 n1 = umax64(p1, q1);
            p2 = umax64(umin64(p1, q1), umax64(p2, q2));
            p1 = n1;
        }
        idx_s[t] = keyv(p1);
        if (keyscore(p1) - keyscore(p2) < EPS_GAP){
            const unsigned p = atomicAdd(cnt, 1u);
            list[p] = (int)(rbase + t);
        }
    }
    __syncthreads();

    // fused gather: 32 rows x 512 floats, 2 rows / iteration
    for (int rr = 0; rr < 32; rr += 2){
        const int row  = rr + (t >> 7);
        const int col  = (t & 127) << 2;
        const int vidx = idx_s[row];
        const float4 val = *(const float4*)(w + (long)vidx * DIM + col);
        *(float4*)(out + (rbase + row) * DIM + col) = val;
    }
}

// ---- exact fp32 re-check + rewrite for flagged (near-tie) rows, BATCHED ----
// 8 rows per block: x rows staged in LDS (16KB), each thread scores 2 codes
// for all 8 rows (w read once per batch from L2), then per-row argmax + rewrite.
__global__ void refine_rows(const float* __restrict__ x, const float* __restrict__ w,
                            const float* __restrict__ cg, const int* __restrict__ list,
                            const unsigned* __restrict__ cnt, float* __restrict__ out){
    __shared__ __align__(16) float xs[RBATCH][DIM];
    __shared__ u64 wk[RBATCH][4];
    __shared__ int bestv_s[RBATCH];
    const int t = threadIdx.x;
    const int lane = t & 63, wvq = t >> 6;
    const int n = (int)*cnt;
    for (int base = blockIdx.x * RBATCH; base < n; base += gridDim.x * RBATCH){
        const int m = (n - base < RBATCH) ? (n - base) : RBATCH;
        __syncthreads();   // protect xs/bestv_s reuse across iterations
        for (int s = t; s < m * 128; s += 256){
            const int r = s >> 7, c = (s & 127) << 2;
            *(float4*)&xs[r][c] = *(const float4*)(x + (long)list[base + r] * DIM + c);
        }
        __syncthreads();
        u64 best[RBATCH];
        #pragma unroll
        for (int r = 0; r < RBATCH; ++r) best[r] = 0;
        #pragma unroll
        for (int vv = 0; vv < 2; ++vv){
            const int v = t + vv * 256;
            const float* wr = w + (long)v * DIM;
            float s[RBATCH];
            #pragma unroll
            for (int r = 0; r < RBATCH; ++r) s[r] = -0.5f * cg[v];
            for (int k = 0; k < DIM; k += 4){
                const float4 w4 = *(const float4*)(wr + k);
                #pragma unroll
                for (int r = 0; r < RBATCH; ++r){
                    const float4 x4 = *(const float4*)&xs[r][k];
                    s[r] = fmaf(w4.x, x4.x, s[r]);
                    s[r] = fmaf(w4.y, x4.y, s[r]);
                    s[r] = fmaf(w4.z, x4.z, s[r]);
                    s[r] = fmaf(w4.w, x4.w, s[r]);
                }
            }
            #pragma unroll
            for (int r = 0; r < RBATCH; ++r)
                best[r] = umax64(best[r], packkey(s[r], v));
        }
        #pragma unroll
        for (int r = 0; r < RBATCH; ++r){
            u64 b = best[r];
            #pragma unroll
            for (int mm = 1; mm <= 32; mm <<= 1) b = umax64(b, __shfl_xor(b, mm, 64));
            if (lane == 0) wk[r][wvq] = b;
        }
        __syncthreads();
        if (t < RBATCH){
            const u64 b = umax64(umax64(wk[t][0], wk[t][1]), umax64(wk[t][2], wk[t][3]));
            bestv_s[t] = keyv(b);
        }
        __syncthreads();
        for (int s = t; s < m * 128; s += 256){
            const int r = s >> 7, c = (s & 127) << 2;
            *(float4*)(out + (long)list[base + r] * DIM + c) =
                *(const float4*)(w + (long)bestv_s[r] * DIM + c);
        }
    }
}

// ---- fallback: round-1 fp32 kernel (self-contained, no ws) ----
__launch_bounds__(256)
__global__ void fallback_full(const float* __restrict__ x, const float* __restrict__ w,
                              float* __restrict__ out){
    __shared__ __align__(16) float As[16][68];
    __shared__ __align__(16) float Bs[16][VOCAB];
    __shared__ int   idx_sf[64];
    __shared__ float c_s[VOCAB];

    const int t  = threadIdx.x;
    const int tx = t & 31;
    const int ty = t >> 5;
    const long rbase = (long)blockIdx.x * 64;
    const float* xblk = x + rbase * DIM;

    for (int vv = t; vv < VOCAB; vv += 256){
        double s = 0.0;
        for (int i = 0; i < DIM; ++i){
            const float wvv = w[i * VOCAB + vv];
            s += (double)wvv * (double)wvv;
        }
        c_s[vv] = (float)s;
    }

    float acc[8][16];
    #pragma unroll
    for (int r = 0; r < 8; ++r)
        #pragma unroll
        for (int j = 0; j < 16; ++j) acc[r][j] = 0.0f;

    for (int k0 = 0; k0 < DIM; k0 += 16){
        __syncthreads();
        {
            const int r  = t >> 2;
            const int kq = (t & 3) << 2;
            const float4 a4 = *(const float4*)(xblk + (long)r * DIM + k0 + kq);
            As[kq + 0][r] = a4.x; As[kq + 1][r] = a4.y;
            As[kq + 2][r] = a4.z; As[kq + 3][r] = a4.w;
        }
        #pragma unroll
        for (int vb = 0; vb < 8; ++vb){
            const int v  = (t >> 2) + (vb << 6);
            const int kq = (t & 3) << 2;
            const float4 b4 = *(const float4*)(w + (long)v * DIM + k0 + kq);
            Bs[kq + 0][v] = b4.x; Bs[kq + 1][v] = b4.y;
            Bs[kq + 2][v] = b4.z; Bs[kq + 3][v] = b4.w;
        }
        __syncthreads();

        #pragma unroll
        for (int k = 0; k < 16; ++k){
            float a[8];
            const float4 a03 = *(const float4*)&As[k][ty * 8];
            const float4 a47 = *(const float4*)&As[k][ty * 8 + 4];
            a[0] = a03.x; a[1] = a03.y; a[2] = a03.z; a[3] = a03.w;
            a[4] = a47.x; a[5] = a47.y; a[6] = a47.z; a[7] = a47.w;
            float b[16];
            #pragma unroll
            for (int j = 0; j < 16; ++j) b[j] = Bs[k][tx + (j << 5)];
            #pragma unroll
            for (int r = 0; r < 8; ++r)
                #pragma unroll
                for (int j = 0; j < 16; ++j)
                    acc[r][j] = fmaf(a[r], b[j], acc[r][j]);
        }
    }

    #pragma unroll
    for (int r = 0; r < 8; ++r){
        float best = acc[r][0] - 0.5f * c_s[tx];
        int   bv   = tx;
        #pragma unroll
        for (int j = 1; j < 16; ++j){
            const float s = acc[r][j] - 0.5f * c_s[tx + (j << 5)];
            if (s > best){ best = s; bv = tx + (j << 5); }
        }
        unsigned u = __float_as_uint(best);
        u = (u & 0x80000000u) ? ~u : (u | 0x80000000u);
        u64 key = ((u64)u << 32) | (unsigned)(~(unsigned)bv);
        #pragma unroll
        for (int m = 1; m <= 16; m <<= 1){
            const u64 o = __shfl_xor(key, m, 64);
            if (o > key) key = o;
        }
        if (tx == 0) idx_sf[ty * 8 + r] = (int)(~(unsigned)(key & 0xFFFFFFFFull));
    }
    __syncthreads();

    for (int rr = 0; rr < 64; rr += 2){
        const int row  = rr + (t >> 7);
        const int col  = (t & 127) << 2;
        const int vidx = idx_sf[row];
        const float4 val = *(const float4*)(w + (long)vidx * DIM + col);
        *(float4*)(out + (rbase + row) * DIM + col) = val;
    }
}

extern "C" void kernel_launch(void* const* d_in, const int* in_sizes, int n_in,
                              void* d_out, int out_size, void* d_ws, size_t ws_size,
                              hipStream_t stream){
    const float* x = (const float*)d_in[0];
    const float* w = (const float*)d_in[1];
    float* out = (float*)d_out;
    const int rows = in_sizes[0] / DIM;        // 65536

    // ws layout (bytes)
    const size_t whc_off  = 0;
    const size_t c_off    = whc_off + (size_t)DIM * VOCAB * 2;   // 512KB fp16 w
    const size_t list_off = c_off   + (size_t)VOCAB * 4;
    const size_t cnt_off  = list_off + (size_t)rows * 4;
    const size_t need     = cnt_off + 16;

    if (ws_size >= need){
        _Float16* whc  = (_Float16*)((char*)d_ws + whc_off);
        float*    c    = (float*)((char*)d_ws + c_off);
        int*      list = (int*)((char*)d_ws + list_off);
        unsigned* cnt  = (unsigned*)((char*)d_ws + cnt_off);

        prep_w<<<(DIM * VOCAB) / 256, 256, 0, stream>>>(w, whc, cnt);
        colsumsq_kernel<<<VOCAB, 64, 0, stream>>>(w, c);
        k1_scores<<<rows / 32, 256, 0, stream>>>(x, whc, c, w, out, list, cnt);
        refine_rows<<<512, 256, 0, stream>>>(x, w, c, list, cnt, out);
    } else {
        fallback_full<<<rows / 64, 256, 0, stream>>>(x, w, out);
    }
}